// Round 1
// baseline (7525.792 us; speedup 1.0000x reference)
//
#include <hip/hip_runtime.h>
#include <hip/hip_bf16.h>
#include <math.h>

// ---------------- problem constants ----------------
constexpr int T_STEPS = 256;
constexpr int HDIM    = 1024;
constexpr int EDIM    = 512;
constexpr int VDIM    = 32000;

// recurrence decomposition
#define RG     128          // persistent workgroups (all co-resident: 128 <= 256 CUs)
#define RROWS  8            // rows owned per WG = HDIM / RG

// ---------------- ws layout (float offsets) ----------------
constexpr size_t WS_BZ    = 0;                                   // [T][H] e@wzx.T + wzx_b + wzh_b
constexpr size_t WS_BR    = WS_BZ + (size_t)T_STEPS * HDIM;      // [T][H]
constexpr size_t WS_A     = WS_BR + (size_t)T_STEPS * HDIM;      // [T][H] e@whx.T + whx_b + whh_b
constexpr size_t WS_HBUF  = WS_A  + (size_t)T_STEPS * HDIM;      // [T+1][H] hidden states
constexpr size_t WS_RH    = WS_HBUF + (size_t)(T_STEPS + 1) * HDIM; // [H] r*h exchange
constexpr size_t WS_FLAGS = WS_RH + HDIM;                        // ints: [0..RG)=flagRH, [RG..2RG)=flagH

__device__ __forceinline__ float sigmoidf_(float x) { return 1.0f / (1.0f + __expf(-x)); }

// ---------------- init: zero flags (ws not re-poisoned between replays!), h0 = encoding ----------------
__global__ __launch_bounds__(256) void k_init(const float* __restrict__ enc, float* __restrict__ ws) {
  int tid = threadIdx.x;
  int* flags = (int*)(ws + WS_FLAGS);
  if (tid < 2 * RG) flags[tid] = 0;
  float* h0 = ws + WS_HBUF;
  for (int i = tid; i < HDIM; i += 256) h0[i] = enc[i];
}

// ---------------- batched e-projections: Bz/Br/A for all t ----------------
// grid: 192 blocks = 16 t-tiles (16 t each) x 12 chunks (3 mats x 4 j-chunks of 256)
__global__ __launch_bounds__(256) void k_xproj(
    const int* __restrict__ tokens, const float* __restrict__ emb,
    const float* __restrict__ wzx, const float* __restrict__ wrx, const float* __restrict__ whx,
    const float* __restrict__ bzx, const float* __restrict__ bzh,
    const float* __restrict__ brx, const float* __restrict__ brh,
    const float* __restrict__ bhx, const float* __restrict__ bhh,
    float* __restrict__ ws) {
  __shared__ __align__(16) float es[16][EDIM];   // 32 KiB
  const int b   = blockIdx.x;
  const int t0  = (b & 15) * 16;
  const int c   = b >> 4;                 // 0..11
  const int tid = threadIdx.x;

  // stage 16 embedding rows
  {
    int row = tid >> 4;                   // 0..15
    int kc  = (tid & 15) * 32;            // 32 floats each
    int tok = tokens[t0 + row];
    const float4* ep = (const float4*)(emb + (size_t)tok * EDIM + kc);
    float4* dst = (float4*)&es[row][kc];
    #pragma unroll
    for (int q = 0; q < 8; q++) dst[q] = ep[q];
  }
  __syncthreads();

  const int mat = c >> 2;
  const int j   = (c & 3) * 256 + tid;
  const float* W; const float* b1; const float* b2; float* Xout;
  if (mat == 0)      { W = wzx; b1 = bzx; b2 = bzh; Xout = ws + WS_BZ; }
  else if (mat == 1) { W = wrx; b1 = brx; b2 = brh; Xout = ws + WS_BR; }
  else               { W = whx; b1 = bhx; b2 = bhh; Xout = ws + WS_A;  }

  const float4* wp = (const float4*)(W + (size_t)j * EDIM);
  const float bias = b1[j] + b2[j];
  float acc[16];
  #pragma unroll
  for (int tt = 0; tt < 16; tt++) acc[tt] = 0.0f;

  for (int k4 = 0; k4 < EDIM / 4; k4++) {
    float4 w = wp[k4];
    #pragma unroll
    for (int tt = 0; tt < 16; tt++) {
      float4 e4 = *(const float4*)&es[tt][k4 * 4];
      acc[tt] += w.x * e4.x + w.y * e4.y + w.z * e4.z + w.w * e4.w;
    }
  }
  #pragma unroll
  for (int tt = 0; tt < 16; tt++)
    Xout[(size_t)(t0 + tt) * HDIM + j] = acc[tt] + bias;
}

// ---------------- persistent GRU recurrence ----------------
// 128 WGs x 256 threads. WG g owns rows [g*8, g*8+8) of wzh/wrh/whh, weights in registers.
// Per step: round A computes z,r (+publish r*h), round B computes v=whh@(r*h) and h_new.
// Cross-WG data goes through agent-scope atomics (coherent across XCDs); flags give ordering.
__global__ __launch_bounds__(256) void k_recur(
    const float* __restrict__ wzh, const float* __restrict__ wrh, const float* __restrict__ whh,
    float* __restrict__ ws) {
  const int g    = blockIdx.x;
  const int tid  = threadIdx.x;
  const int lane = tid & 63;
  const int wv   = tid >> 6;
  const float* Bz = ws + WS_BZ;
  const float* Br = ws + WS_BR;
  const float* Aa = ws + WS_A;
  float* hbuf  = ws + WS_HBUF;
  float* rhb   = ws + WS_RH;
  int* flagRH  = (int*)(ws + WS_FLAGS);
  int* flagH   = flagRH + RG;

  const int j0 = 4 * tid;          // this thread's h-slice [j0, j0+4)
  const int r0 = g * RROWS;        // this WG's row base

  // register-resident weights: 3 x 8 rows x 4 cols = 96 floats
  float4 wz[RROWS], wr[RROWS], wh[RROWS];
  #pragma unroll
  for (int k = 0; k < RROWS; k++) {
    wz[k] = *(const float4*)(wzh + (size_t)(r0 + k) * HDIM + j0);
    wr[k] = *(const float4*)(wrh + (size_t)(r0 + k) * HDIM + j0);
    wh[k] = *(const float4*)(whh + (size_t)(r0 + k) * HDIM + j0);
  }

  __shared__ float red[4][2 * RROWS];
  __shared__ float zs[RROWS];
  __shared__ float hloc[RROWS];
  if (tid < RROWS) hloc[tid] = hbuf[r0 + tid];   // h0 row slice (written by k_init)

  const int pollidx = tid >> 1;    // producer WG of rows [4*tid, 4*tid+4)  (4 rows within one 8-row group)

  for (int t = 0; t < T_STEPS; t++) {
    // prefetch read-only per-step constants (safe before sync: written before this kernel)
    float bz_pre = 0.0f, br_pre = 0.0f, a_pre = 0.0f;
    if (tid < RROWS) {
      bz_pre = Bz[(size_t)t * HDIM + r0 + tid];
      a_pre  = Aa[(size_t)t * HDIM + r0 + tid];
    } else if (tid < 2 * RROWS) {
      br_pre = Br[(size_t)t * HDIM + r0 + (tid - RROWS)];
    }

    // ================= round A: z, r, publish r*h =================
    if (t > 0) {
      int it = 0;
      while (__hip_atomic_load(&flagH[pollidx], __ATOMIC_ACQUIRE, __HIP_MEMORY_SCOPE_AGENT) < t) {
        __builtin_amdgcn_s_sleep(1);
        if (++it > (1 << 18)) break;   // safety: garbage instead of hang
      }
    }
    float hv0 = __hip_atomic_load(&hbuf[(size_t)t * HDIM + j0 + 0], __ATOMIC_RELAXED, __HIP_MEMORY_SCOPE_AGENT);
    float hv1 = __hip_atomic_load(&hbuf[(size_t)t * HDIM + j0 + 1], __ATOMIC_RELAXED, __HIP_MEMORY_SCOPE_AGENT);
    float hv2 = __hip_atomic_load(&hbuf[(size_t)t * HDIM + j0 + 2], __ATOMIC_RELAXED, __HIP_MEMORY_SCOPE_AGENT);
    float hv3 = __hip_atomic_load(&hbuf[(size_t)t * HDIM + j0 + 3], __ATOMIC_RELAXED, __HIP_MEMORY_SCOPE_AGENT);

    float pz[RROWS], pr[RROWS];
    #pragma unroll
    for (int k = 0; k < RROWS; k++) {
      pz[k] = wz[k].x * hv0 + wz[k].y * hv1 + wz[k].z * hv2 + wz[k].w * hv3;
      pr[k] = wr[k].x * hv0 + wr[k].y * hv1 + wr[k].z * hv2 + wr[k].w * hv3;
    }
    #pragma unroll
    for (int m = 32; m >= 1; m >>= 1) {
      #pragma unroll
      for (int k = 0; k < RROWS; k++) {
        pz[k] += __shfl_xor(pz[k], m);
        pr[k] += __shfl_xor(pr[k], m);
      }
    }
    if (lane == 0) {
      #pragma unroll
      for (int k = 0; k < RROWS; k++) { red[wv][k] = pz[k]; red[wv][RROWS + k] = pr[k]; }
    }
    __syncthreads();
    if (tid < RROWS) {
      float u = red[0][tid] + red[1][tid] + red[2][tid] + red[3][tid];
      zs[tid] = sigmoidf_(bz_pre + u);
    } else if (tid < 2 * RROWS) {
      int k = tid - RROWS;
      float u = red[0][tid] + red[1][tid] + red[2][tid] + red[3][tid];
      float r = sigmoidf_(br_pre + u);
      float rh = r * hloc[k];
      __hip_atomic_store(&rhb[r0 + k], rh, __ATOMIC_RELAXED, __HIP_MEMORY_SCOPE_AGENT);
    }
    if (tid == 0)
      __hip_atomic_store(&flagRH[g], t + 1, __ATOMIC_RELEASE, __HIP_MEMORY_SCOPE_AGENT);

    // ================= round B: v = whh@(r*h), h_new =================
    {
      int it = 0;
      while (__hip_atomic_load(&flagRH[pollidx], __ATOMIC_ACQUIRE, __HIP_MEMORY_SCOPE_AGENT) < t + 1) {
        __builtin_amdgcn_s_sleep(1);
        if (++it > (1 << 18)) break;
      }
    }
    float rv0 = __hip_atomic_load(&rhb[j0 + 0], __ATOMIC_RELAXED, __HIP_MEMORY_SCOPE_AGENT);
    float rv1 = __hip_atomic_load(&rhb[j0 + 1], __ATOMIC_RELAXED, __HIP_MEMORY_SCOPE_AGENT);
    float rv2 = __hip_atomic_load(&rhb[j0 + 2], __ATOMIC_RELAXED, __HIP_MEMORY_SCOPE_AGENT);
    float rv3 = __hip_atomic_load(&rhb[j0 + 3], __ATOMIC_RELAXED, __HIP_MEMORY_SCOPE_AGENT);

    float ph[RROWS];
    #pragma unroll
    for (int k = 0; k < RROWS; k++)
      ph[k] = wh[k].x * rv0 + wh[k].y * rv1 + wh[k].z * rv2 + wh[k].w * rv3;
    #pragma unroll
    for (int m = 32; m >= 1; m >>= 1) {
      #pragma unroll
      for (int k = 0; k < RROWS; k++) ph[k] += __shfl_xor(ph[k], m);
    }
    if (lane == 0) {
      #pragma unroll
      for (int k = 0; k < RROWS; k++) red[wv][k] = ph[k];
    }
    __syncthreads();
    if (tid < RROWS) {
      float v  = red[0][tid] + red[1][tid] + red[2][tid] + red[3][tid];
      float z  = zs[tid];
      float hk = hloc[tid];
      float hp = tanhf(a_pre + v);
      float hn = (1.0f - z) * hk + z * hp;
      hloc[tid] = hn;
      __hip_atomic_store(&hbuf[(size_t)(t + 1) * HDIM + r0 + tid], hn,
                         __ATOMIC_RELAXED, __HIP_MEMORY_SCOPE_AGENT);
    }
    if (tid == 0)
      __hip_atomic_store(&flagH[g], t + 1, __ATOMIC_RELEASE, __HIP_MEMORY_SCOPE_AGENT);
  }
}

// ---------------- logits GEMM: [256,1024] @ out_w[32000,1024]^T + out_b ----------------
// fp32, 128x128 tile, BK=16, 8x8 micro-tile. grid (2 m-tiles, 250 n-tiles) so the two
// m-tiles sharing a B-panel are dispatch-adjacent (L2 reuse of out_w).
__global__ __launch_bounds__(256) void k_gemm(
    const float* __restrict__ hseq, const float* __restrict__ outw,
    const float* __restrict__ outb, float* __restrict__ out) {
  __shared__ __align__(16) float As[16][132];
  __shared__ __align__(16) float Bs[16][132];
  const int tid = threadIdx.x;
  const int m0 = blockIdx.x * 128;
  const int n0 = blockIdx.y * 128;
  const int tx = tid & 15, ty = tid >> 4;
  const int lr = tid >> 1;           // 0..127 tile row
  const int lc = (tid & 1) * 8;      // k sub-chunk
  const float* Ag = hseq + (size_t)(m0 + lr) * HDIM + lc;
  const float* Bg = outw + (size_t)(n0 + lr) * HDIM + lc;

  float acc[8][8];
  #pragma unroll
  for (int i = 0; i < 8; i++)
    #pragma unroll
    for (int j = 0; j < 8; j++) acc[i][j] = 0.0f;

  for (int k0 = 0; k0 < HDIM; k0 += 16) {
    float4 a0 = *(const float4*)(Ag + k0);
    float4 a1 = *(const float4*)(Ag + k0 + 4);
    float4 b0 = *(const float4*)(Bg + k0);
    float4 b1 = *(const float4*)(Bg + k0 + 4);
    __syncthreads();
    As[lc + 0][lr] = a0.x; As[lc + 1][lr] = a0.y; As[lc + 2][lr] = a0.z; As[lc + 3][lr] = a0.w;
    As[lc + 4][lr] = a1.x; As[lc + 5][lr] = a1.y; As[lc + 6][lr] = a1.z; As[lc + 7][lr] = a1.w;
    Bs[lc + 0][lr] = b0.x; Bs[lc + 1][lr] = b0.y; Bs[lc + 2][lr] = b0.z; Bs[lc + 3][lr] = b0.w;
    Bs[lc + 4][lr] = b1.x; Bs[lc + 5][lr] = b1.y; Bs[lc + 6][lr] = b1.z; Bs[lc + 7][lr] = b1.w;
    __syncthreads();
    #pragma unroll
    for (int kk = 0; kk < 16; kk++) {
      float4 av0 = *(const float4*)&As[kk][ty * 8];
      float4 av1 = *(const float4*)&As[kk][ty * 8 + 4];
      float4 bv0 = *(const float4*)&Bs[kk][tx * 8];
      float4 bv1 = *(const float4*)&Bs[kk][tx * 8 + 4];
      float am[8] = {av0.x, av0.y, av0.z, av0.w, av1.x, av1.y, av1.z, av1.w};
      float bn[8] = {bv0.x, bv0.y, bv0.z, bv0.w, bv1.x, bv1.y, bv1.z, bv1.w};
      #pragma unroll
      for (int i = 0; i < 8; i++)
        #pragma unroll
        for (int j = 0; j < 8; j++) acc[i][j] += am[i] * bn[j];
    }
  }

  float4 ob0 = *(const float4*)(outb + n0 + tx * 8);
  float4 ob1 = *(const float4*)(outb + n0 + tx * 8 + 4);
  float bn[8] = {ob0.x, ob0.y, ob0.z, ob0.w, ob1.x, ob1.y, ob1.z, ob1.w};
  #pragma unroll
  for (int i = 0; i < 8; i++) {
    int row = m0 + ty * 8 + i;
    float* op = out + (size_t)row * VDIM + n0 + tx * 8;
    float4 c0 = make_float4(acc[i][0] + bn[0], acc[i][1] + bn[1], acc[i][2] + bn[2], acc[i][3] + bn[3]);
    float4 c1 = make_float4(acc[i][4] + bn[4], acc[i][5] + bn[5], acc[i][6] + bn[6], acc[i][7] + bn[7]);
    *(float4*)op = c0;
    *(float4*)(op + 4) = c1;
  }
}

// ---------------- argmax per row, first-index tie rule (matches jnp.argmax) ----------------
__global__ __launch_bounds__(256) void k_argmax(const float* __restrict__ logits,
                                                float* __restrict__ outids) {
  const int t = blockIdx.x;
  const int tid = threadIdx.x;
  const float* row = logits + (size_t)t * VDIM;
  float best = -3.4e38f; int bi = 0;
  for (int v = tid; v < VDIM; v += 256) {
    float x = row[v];
    if (x > best) { best = x; bi = v; }
  }
  __shared__ float bv[256];
  __shared__ int  bidx[256];
  bv[tid] = best; bidx[tid] = bi;
  __syncthreads();
  for (int s = 128; s > 0; s >>= 1) {
    if (tid < s) {
      if (bv[tid + s] > bv[tid] || (bv[tid + s] == bv[tid] && bidx[tid + s] < bidx[tid])) {
        bv[tid] = bv[tid + s]; bidx[tid] = bidx[tid + s];
      }
    }
    __syncthreads();
  }
  if (tid == 0) outids[t] = (float)bidx[0];
}

// ---------------- launch ----------------
extern "C" void kernel_launch(void* const* d_in, const int* in_sizes, int n_in,
                              void* d_out, int out_size, void* d_ws, size_t ws_size,
                              hipStream_t stream) {
  (void)in_sizes; (void)n_in; (void)out_size; (void)ws_size;
  const float* enc    = (const float*)d_in[0];
  const int*   tokens = (const int*)d_in[1];
  const float* emb    = (const float*)d_in[2];
  const float* wzx_w  = (const float*)d_in[3];
  const float* wzx_b  = (const float*)d_in[4];
  const float* wrx_w  = (const float*)d_in[5];
  const float* wrx_b  = (const float*)d_in[6];
  const float* whx_w  = (const float*)d_in[7];
  const float* whx_b  = (const float*)d_in[8];
  const float* wzh_w  = (const float*)d_in[9];
  const float* wzh_b  = (const float*)d_in[10];
  const float* wrh_w  = (const float*)d_in[11];
  const float* wrh_b  = (const float*)d_in[12];
  const float* whh_w  = (const float*)d_in[13];
  const float* whh_b  = (const float*)d_in[14];
  const float* out_w  = (const float*)d_in[15];
  const float* out_b  = (const float*)d_in[16];
  float* ws  = (float*)d_ws;
  float* out = (float*)d_out;

  k_init<<<dim3(1), dim3(256), 0, stream>>>(enc, ws);
  k_xproj<<<dim3(192), dim3(256), 0, stream>>>(tokens, emb, wzx_w, wrx_w, whx_w,
                                               wzx_b, wzh_b, wrx_b, wrh_b, whx_b, whh_b, ws);
  k_recur<<<dim3(RG), dim3(256), 0, stream>>>(wzh_w, wrh_w, whh_w, ws);
  k_gemm<<<dim3(2, 250), dim3(256), 0, stream>>>(ws + WS_HBUF + HDIM, out_w, out_b, out);
  k_argmax<<<dim3(256), dim3(256), 0, stream>>>(out, out + (size_t)T_STEPS * VDIM);
}

// Round 2
// 1498.050 us; speedup vs baseline: 5.0237x; 5.0237x over previous
//
#include <hip/hip_runtime.h>
#include <hip/hip_bf16.h>
#include <math.h>

// ---------------- problem constants ----------------
constexpr int T_STEPS = 256;
constexpr int HDIM    = 1024;
constexpr int EDIM    = 512;
constexpr int VDIM    = 32000;

// recurrence decomposition
#define RG     128          // persistent workgroups (all co-resident: 128 <= 256 CUs)
#define RROWS  8            // rows owned per WG = HDIM / RG

// ---------------- ws layout (float offsets) ----------------
// Bz region is overlaid by hseq during k_recur: hseq[t] (=h_{t+1}) is written only
// after every WG has read its Bz[t] slice (proof: any hseq[t] write requires all WGs'
// round-A rh publishes for step t, each of which follows that WG's Bz[t] prefetch).
constexpr size_t WS_BZ     = 0;                                   // [T][H] e@wzx.T + biases
constexpr size_t WS_BR     = WS_BZ + (size_t)T_STEPS * HDIM;      // [T][H]
constexpr size_t WS_A      = WS_BR + (size_t)T_STEPS * HDIM;      // [T][H]
constexpr size_t WS_HPACK  = WS_A  + (size_t)T_STEPS * HDIM;      // ull[(T+1)][H]: (tag<<32)|bits, tag of h_s = s+1
constexpr size_t WS_RHPACK = WS_HPACK + (size_t)2 * (T_STEPS + 1) * HDIM; // ull[H], tag = t+1
constexpr size_t WS_HSEQ   = WS_BZ;                               // [T][H] h_1..h_256 (GEMM A), overlay

__device__ __forceinline__ float sigmoidf_(float x) { return 1.0f / (1.0f + __expf(-x)); }

__device__ __forceinline__ unsigned long long pack_tv(int tag, float v) {
  return ((unsigned long long)(unsigned)tag << 32) | (unsigned long long)__float_as_uint(v);
}

// ---------------- init: clear tags (ws NOT re-poisoned between replays), pack h0 ----------------
// grid 258: block 0 packs h0 (tag 1); blocks 1..256 clear hpack row b; block 257 clears rhpack.
__global__ __launch_bounds__(256) void k_init(const float* __restrict__ enc, float* __restrict__ ws) {
  unsigned long long* hpack  = (unsigned long long*)(ws + WS_HPACK);
  unsigned long long* rhpack = (unsigned long long*)(ws + WS_RHPACK);
  const int b = blockIdx.x, tid = threadIdx.x;
  if (b == 0) {
    for (int i = tid; i < HDIM; i += 256) hpack[i] = pack_tv(1, enc[i]);
  } else if (b <= T_STEPS) {
    unsigned long long* row = hpack + (size_t)b * HDIM;
    for (int i = tid; i < HDIM; i += 256) row[i] = 0ULL;
  } else {
    for (int i = tid; i < HDIM; i += 256) rhpack[i] = 0ULL;
  }
}

// ---------------- batched e-projections: Bz/Br/A for all t ----------------
__global__ __launch_bounds__(256) void k_xproj(
    const int* __restrict__ tokens, const float* __restrict__ emb,
    const float* __restrict__ wzx, const float* __restrict__ wrx, const float* __restrict__ whx,
    const float* __restrict__ bzx, const float* __restrict__ bzh,
    const float* __restrict__ brx, const float* __restrict__ brh,
    const float* __restrict__ bhx, const float* __restrict__ bhh,
    float* __restrict__ ws) {
  __shared__ __align__(16) float es[16][EDIM];   // 32 KiB
  const int b   = blockIdx.x;
  const int t0  = (b & 15) * 16;
  const int c   = b >> 4;                 // 0..11
  const int tid = threadIdx.x;

  {
    int row = tid >> 4;
    int kc  = (tid & 15) * 32;
    int tok = tokens[t0 + row];
    const float4* ep = (const float4*)(emb + (size_t)tok * EDIM + kc);
    float4* dst = (float4*)&es[row][kc];
    #pragma unroll
    for (int q = 0; q < 8; q++) dst[q] = ep[q];
  }
  __syncthreads();

  const int mat = c >> 2;
  const int j   = (c & 3) * 256 + tid;
  const float* W; const float* b1; const float* b2; float* Xout;
  if (mat == 0)      { W = wzx; b1 = bzx; b2 = bzh; Xout = ws + WS_BZ; }
  else if (mat == 1) { W = wrx; b1 = brx; b2 = brh; Xout = ws + WS_BR; }
  else               { W = whx; b1 = bhx; b2 = bhh; Xout = ws + WS_A;  }

  const float4* wp = (const float4*)(W + (size_t)j * EDIM);
  const float bias = b1[j] + b2[j];
  float acc[16];
  #pragma unroll
  for (int tt = 0; tt < 16; tt++) acc[tt] = 0.0f;

  for (int k4 = 0; k4 < EDIM / 4; k4++) {
    float4 w = wp[k4];
    #pragma unroll
    for (int tt = 0; tt < 16; tt++) {
      float4 e4 = *(const float4*)&es[tt][k4 * 4];
      acc[tt] += w.x * e4.x + w.y * e4.y + w.z * e4.z + w.w * e4.w;
    }
  }
  #pragma unroll
  for (int tt = 0; tt < 16; tt++)
    Xout[(size_t)(t0 + tt) * HDIM + j] = acc[tt] + bias;
}

// ---------------- persistent GRU recurrence, fence-free sync ----------------
// All cross-WG exchange via 64-bit RELAXED agent-scope atomics carrying (tag|value).
// No acquire/release => no buffer_inv / buffer_wb cache maintenance in the spin loops.
__global__ __launch_bounds__(256) void k_recur(
    const float* __restrict__ wzh, const float* __restrict__ wrh, const float* __restrict__ whh,
    float* __restrict__ ws) {
  const int g    = blockIdx.x;
  const int tid  = threadIdx.x;
  const int lane = tid & 63;
  const int wv   = tid >> 6;
  const float* Bz = ws + WS_BZ;
  const float* Br = ws + WS_BR;
  const float* Aa = ws + WS_A;
  float* hseq = ws + WS_HSEQ;
  unsigned long long* hpack  = (unsigned long long*)(ws + WS_HPACK);
  unsigned long long* rhpack = (unsigned long long*)(ws + WS_RHPACK);

  const int j0 = 4 * tid;          // this thread's h-slice [j0, j0+4)
  const int r0 = g * RROWS;        // this WG's row base

  // register-resident weights: 3 x 8 rows x 4 cols = 96 floats
  float4 wz[RROWS], wr[RROWS], wh[RROWS];
  #pragma unroll
  for (int k = 0; k < RROWS; k++) {
    wz[k] = *(const float4*)(wzh + (size_t)(r0 + k) * HDIM + j0);
    wr[k] = *(const float4*)(wrh + (size_t)(r0 + k) * HDIM + j0);
    wh[k] = *(const float4*)(whh + (size_t)(r0 + k) * HDIM + j0);
  }

  __shared__ float red[4][2 * RROWS];
  __shared__ float zs[RROWS];
  __shared__ float hloc[RROWS];
  if (tid < RROWS)
    hloc[tid] = __uint_as_float((unsigned)hpack[r0 + tid]);  // h0, written by k_init
  __syncthreads();

  for (int t = 0; t < T_STEPS; t++) {
    // prefetch per-step constants (plain cached loads; written by k_xproj)
    float bz_pre = 0.0f, br_pre = 0.0f, a_pre = 0.0f;
    if (tid < RROWS) {
      bz_pre = Bz[(size_t)t * HDIM + r0 + tid];
      a_pre  = Aa[(size_t)t * HDIM + r0 + tid];
    } else if (tid < 2 * RROWS) {
      br_pre = Br[(size_t)t * HDIM + r0 + (tid - RROWS)];
    }
    const unsigned long long ex = (unsigned long long)(unsigned)(t + 1);

    // ================= round A: z, r, publish r*h =================
    float hv0, hv1, hv2, hv3;
    {
      const unsigned long long* hp = hpack + (size_t)t * HDIM + j0;
      unsigned long long w0, w1, w2, w3;
      int it = 0;
      for (;;) {
        w0 = __hip_atomic_load(hp + 0, __ATOMIC_RELAXED, __HIP_MEMORY_SCOPE_AGENT);
        w1 = __hip_atomic_load(hp + 1, __ATOMIC_RELAXED, __HIP_MEMORY_SCOPE_AGENT);
        w2 = __hip_atomic_load(hp + 2, __ATOMIC_RELAXED, __HIP_MEMORY_SCOPE_AGENT);
        w3 = __hip_atomic_load(hp + 3, __ATOMIC_RELAXED, __HIP_MEMORY_SCOPE_AGENT);
        if (((w0 >> 32) == ex) & ((w1 >> 32) == ex) & ((w2 >> 32) == ex) & ((w3 >> 32) == ex)) break;
        if (++it > (1 << 20)) break;   // safety: garbage instead of hang
        __builtin_amdgcn_s_sleep(1);
      }
      hv0 = __uint_as_float((unsigned)w0);
      hv1 = __uint_as_float((unsigned)w1);
      hv2 = __uint_as_float((unsigned)w2);
      hv3 = __uint_as_float((unsigned)w3);
    }

    float pz[RROWS], pr[RROWS];
    #pragma unroll
    for (int k = 0; k < RROWS; k++) {
      pz[k] = wz[k].x * hv0 + wz[k].y * hv1 + wz[k].z * hv2 + wz[k].w * hv3;
      pr[k] = wr[k].x * hv0 + wr[k].y * hv1 + wr[k].z * hv2 + wr[k].w * hv3;
    }
    #pragma unroll
    for (int m = 32; m >= 1; m >>= 1) {
      #pragma unroll
      for (int k = 0; k < RROWS; k++) {
        pz[k] += __shfl_xor(pz[k], m);
        pr[k] += __shfl_xor(pr[k], m);
      }
    }
    if (lane == 0) {
      #pragma unroll
      for (int k = 0; k < RROWS; k++) { red[wv][k] = pz[k]; red[wv][RROWS + k] = pr[k]; }
    }
    __syncthreads();
    if (tid < RROWS) {
      float u = red[0][tid] + red[1][tid] + red[2][tid] + red[3][tid];
      zs[tid] = sigmoidf_(bz_pre + u);
    } else if (tid < 2 * RROWS) {
      int k = tid - RROWS;
      float u = red[0][tid] + red[1][tid] + red[2][tid] + red[3][tid];
      float r = sigmoidf_(br_pre + u);
      float rh = r * hloc[k];
      __hip_atomic_store(&rhpack[r0 + k], pack_tv(t + 1, rh),
                         __ATOMIC_RELAXED, __HIP_MEMORY_SCOPE_AGENT);
    }

    // ================= round B: v = whh@(r*h), h_new =================
    float rv0, rv1, rv2, rv3;
    {
      const unsigned long long* rp = rhpack + j0;
      unsigned long long w0, w1, w2, w3;
      int it = 0;
      for (;;) {
        w0 = __hip_atomic_load(rp + 0, __ATOMIC_RELAXED, __HIP_MEMORY_SCOPE_AGENT);
        w1 = __hip_atomic_load(rp + 1, __ATOMIC_RELAXED, __HIP_MEMORY_SCOPE_AGENT);
        w2 = __hip_atomic_load(rp + 2, __ATOMIC_RELAXED, __HIP_MEMORY_SCOPE_AGENT);
        w3 = __hip_atomic_load(rp + 3, __ATOMIC_RELAXED, __HIP_MEMORY_SCOPE_AGENT);
        if (((w0 >> 32) == ex) & ((w1 >> 32) == ex) & ((w2 >> 32) == ex) & ((w3 >> 32) == ex)) break;
        if (++it > (1 << 20)) break;
        __builtin_amdgcn_s_sleep(1);
      }
      rv0 = __uint_as_float((unsigned)w0);
      rv1 = __uint_as_float((unsigned)w1);
      rv2 = __uint_as_float((unsigned)w2);
      rv3 = __uint_as_float((unsigned)w3);
    }

    float ph[RROWS];
    #pragma unroll
    for (int k = 0; k < RROWS; k++)
      ph[k] = wh[k].x * rv0 + wh[k].y * rv1 + wh[k].z * rv2 + wh[k].w * rv3;
    #pragma unroll
    for (int m = 32; m >= 1; m >>= 1) {
      #pragma unroll
      for (int k = 0; k < RROWS; k++) ph[k] += __shfl_xor(ph[k], m);
    }
    if (lane == 0) {
      #pragma unroll
      for (int k = 0; k < RROWS; k++) red[wv][k] = ph[k];
    }
    __syncthreads();
    if (tid < RROWS) {
      float v  = red[0][tid] + red[1][tid] + red[2][tid] + red[3][tid];
      float z  = zs[tid];
      float hk = hloc[tid];
      float hp_ = tanhf(a_pre + v);
      float hn = (1.0f - z) * hk + z * hp_;
      hloc[tid] = hn;
      // publish h_{t+1}: tag = (t+1)+1
      __hip_atomic_store(&hpack[(size_t)(t + 1) * HDIM + r0 + tid], pack_tv(t + 2, hn),
                         __ATOMIC_RELAXED, __HIP_MEMORY_SCOPE_AGENT);
      hseq[(size_t)t * HDIM + r0 + tid] = hn;   // plain store, consumed by k_gemm after kernel end
    }
  }
}

// ---------------- logits GEMM: [256,1024] @ out_w[32000,1024]^T + out_b ----------------
__global__ __launch_bounds__(256) void k_gemm(
    const float* __restrict__ hseq, const float* __restrict__ outw,
    const float* __restrict__ outb, float* __restrict__ out) {
  __shared__ __align__(16) float As[16][132];
  __shared__ __align__(16) float Bs[16][132];
  const int tid = threadIdx.x;
  const int m0 = blockIdx.x * 128;
  const int n0 = blockIdx.y * 128;
  const int tx = tid & 15, ty = tid >> 4;
  const int lr = tid >> 1;
  const int lc = (tid & 1) * 8;
  const float* Ag = hseq + (size_t)(m0 + lr) * HDIM + lc;
  const float* Bg = outw + (size_t)(n0 + lr) * HDIM + lc;

  float acc[8][8];
  #pragma unroll
  for (int i = 0; i < 8; i++)
    #pragma unroll
    for (int j = 0; j < 8; j++) acc[i][j] = 0.0f;

  for (int k0 = 0; k0 < HDIM; k0 += 16) {
    float4 a0 = *(const float4*)(Ag + k0);
    float4 a1 = *(const float4*)(Ag + k0 + 4);
    float4 b0 = *(const float4*)(Bg + k0);
    float4 b1 = *(const float4*)(Bg + k0 + 4);
    __syncthreads();
    As[lc + 0][lr] = a0.x; As[lc + 1][lr] = a0.y; As[lc + 2][lr] = a0.z; As[lc + 3][lr] = a0.w;
    As[lc + 4][lr] = a1.x; As[lc + 5][lr] = a1.y; As[lc + 6][lr] = a1.z; As[lc + 7][lr] = a1.w;
    Bs[lc + 0][lr] = b0.x; Bs[lc + 1][lr] = b0.y; Bs[lc + 2][lr] = b0.z; Bs[lc + 3][lr] = b0.w;
    Bs[lc + 4][lr] = b1.x; Bs[lc + 5][lr] = b1.y; Bs[lc + 6][lr] = b1.z; Bs[lc + 7][lr] = b1.w;
    __syncthreads();
    #pragma unroll
    for (int kk = 0; kk < 16; kk++) {
      float4 av0 = *(const float4*)&As[kk][ty * 8];
      float4 av1 = *(const float4*)&As[kk][ty * 8 + 4];
      float4 bv0 = *(const float4*)&Bs[kk][tx * 8];
      float4 bv1 = *(const float4*)&Bs[kk][tx * 8 + 4];
      float am[8] = {av0.x, av0.y, av0.z, av0.w, av1.x, av1.y, av1.z, av1.w};
      float bn[8] = {bv0.x, bv0.y, bv0.z, bv0.w, bv1.x, bv1.y, bv1.z, bv1.w};
      #pragma unroll
      for (int i = 0; i < 8; i++)
        #pragma unroll
        for (int j = 0; j < 8; j++) acc[i][j] += am[i] * bn[j];
    }
  }

  float4 ob0 = *(const float4*)(outb + n0 + tx * 8);
  float4 ob1 = *(const float4*)(outb + n0 + tx * 8 + 4);
  float bn[8] = {ob0.x, ob0.y, ob0.z, ob0.w, ob1.x, ob1.y, ob1.z, ob1.w};
  #pragma unroll
  for (int i = 0; i < 8; i++) {
    int row = m0 + ty * 8 + i;
    float* op = out + (size_t)row * VDIM + n0 + tx * 8;
    float4 c0 = make_float4(acc[i][0] + bn[0], acc[i][1] + bn[1], acc[i][2] + bn[2], acc[i][3] + bn[3]);
    float4 c1 = make_float4(acc[i][4] + bn[4], acc[i][5] + bn[5], acc[i][6] + bn[6], acc[i][7] + bn[7]);
    *(float4*)op = c0;
    *(float4*)(op + 4) = c1;
  }
}

// ---------------- argmax per row, first-index tie rule ----------------
__global__ __launch_bounds__(256) void k_argmax(const float* __restrict__ logits,
                                                float* __restrict__ outids) {
  const int t = blockIdx.x;
  const int tid = threadIdx.x;
  const float* row = logits + (size_t)t * VDIM;
  float best = -3.4e38f; int bi = 0;
  for (int v = tid; v < VDIM; v += 256) {
    float x = row[v];
    if (x > best) { best = x; bi = v; }
  }
  __shared__ float bv[256];
  __shared__ int  bidx[256];
  bv[tid] = best; bidx[tid] = bi;
  __syncthreads();
  for (int s = 128; s > 0; s >>= 1) {
    if (tid < s) {
      if (bv[tid + s] > bv[tid] || (bv[tid + s] == bv[tid] && bidx[tid + s] < bidx[tid])) {
        bv[tid] = bv[tid + s]; bidx[tid] = bidx[tid + s];
      }
    }
    __syncthreads();
  }
  if (tid == 0) outids[t] = (float)bidx[0];
}

// ---------------- launch ----------------
extern "C" void kernel_launch(void* const* d_in, const int* in_sizes, int n_in,
                              void* d_out, int out_size, void* d_ws, size_t ws_size,
                              hipStream_t stream) {
  (void)in_sizes; (void)n_in; (void)out_size; (void)ws_size;
  const float* enc    = (const float*)d_in[0];
  const int*   tokens = (const int*)d_in[1];
  const float* emb    = (const float*)d_in[2];
  const float* wzx_w  = (const float*)d_in[3];
  const float* wzx_b  = (const float*)d_in[4];
  const float* wrx_w  = (const float*)d_in[5];
  const float* wrx_b  = (const float*)d_in[6];
  const float* whx_w  = (const float*)d_in[7];
  const float* whx_b  = (const float*)d_in[8];
  const float* wzh_w  = (const float*)d_in[9];
  const float* wzh_b  = (const float*)d_in[10];
  const float* wrh_w  = (const float*)d_in[11];
  const float* wrh_b  = (const float*)d_in[12];
  const float* whh_w  = (const float*)d_in[13];
  const float* whh_b  = (const float*)d_in[14];
  const float* out_w  = (const float*)d_in[15];
  const float* out_b  = (const float*)d_in[16];
  float* ws  = (float*)d_ws;
  float* out = (float*)d_out;

  k_init<<<dim3(T_STEPS + 2), dim3(256), 0, stream>>>(enc, ws);
  k_xproj<<<dim3(192), dim3(256), 0, stream>>>(tokens, emb, wzx_w, wrx_w, whx_w,
                                               wzx_b, wzh_b, wrx_b, wrh_b, whx_b, whh_b, ws);
  k_recur<<<dim3(RG), dim3(256), 0, stream>>>(wzh_w, wrh_w, whh_w, ws);
  k_gemm<<<dim3(2, 250), dim3(256), 0, stream>>>(ws + WS_HSEQ, out_w, out_b, out);
  k_argmax<<<dim3(256), dim3(256), 0, stream>>>(out, out + (size_t)T_STEPS * VDIM);
}

// Round 3
// 1434.831 us; speedup vs baseline: 5.2451x; 1.0441x over previous
//
#include <hip/hip_runtime.h>
#include <hip/hip_bf16.h>
#include <math.h>

// ---------------- problem constants ----------------
constexpr int T_STEPS = 256;
constexpr int HDIM    = 1024;
constexpr int EDIM    = 512;
constexpr int VDIM    = 32000;

#define RG     128          // persistent workgroups (1 per CU, all co-resident)
#define RROWS  8            // rows owned per WG = HDIM / RG

// ---------------- ws layout (float offsets) ----------------
// Overlays (all proven safe by publish-chain ordering):
//  - hseq fp32 [T][H] overlays BZ   (hseq[t] written only after all WGs consumed Bz[t])
//  - hseq bf16 [T][H] overlays BR   (same argument; 512 KB < 1 MB region)
constexpr size_t WS_BZ     = 0;                                   // [T][H]
constexpr size_t WS_BR     = WS_BZ + (size_t)T_STEPS * HDIM;      // [T][H]
constexpr size_t WS_A      = WS_BR + (size_t)T_STEPS * HDIM;      // [T][H]
constexpr size_t WS_HPACK  = WS_A  + (size_t)T_STEPS * HDIM;      // ull[(T+1)][H]: (tag<<32)|bits
constexpr size_t WS_RHPACK = WS_HPACK + (size_t)2 * (T_STEPS + 1) * HDIM; // ull[H]
constexpr size_t WS_HSEQ   = WS_BZ;                               // fp32 overlay
constexpr size_t WS_HSEQB  = WS_BR;                               // bf16 overlay (ushort*)

typedef __attribute__((ext_vector_type(8))) short short8;
typedef __attribute__((ext_vector_type(4))) float f32x4;

__device__ __forceinline__ float sigmoidf_(float x) { return 1.0f / (1.0f + __expf(-x)); }

__device__ __forceinline__ unsigned long long pack_tv(int tag, float v) {
  return ((unsigned long long)(unsigned)tag << 32) | (unsigned long long)__float_as_uint(v);
}

__device__ __forceinline__ unsigned short f2bf(float f) {   // RNE fp32 -> bf16 bits
  unsigned u = __float_as_uint(f);
  return (unsigned short)((u + 0x7FFFu + ((u >> 16) & 1u)) >> 16);
}

// ---------------- init: clear tags (ws NOT re-poisoned between replays), pack h0 ----------------
__global__ __launch_bounds__(256) void k_init(const float* __restrict__ enc, float* __restrict__ ws) {
  unsigned long long* hpack  = (unsigned long long*)(ws + WS_HPACK);
  unsigned long long* rhpack = (unsigned long long*)(ws + WS_RHPACK);
  const int b = blockIdx.x, tid = threadIdx.x;
  if (b == 0) {
    for (int i = tid; i < HDIM; i += 256) hpack[i] = pack_tv(1, enc[i]);
  } else if (b <= T_STEPS) {
    unsigned long long* row = hpack + (size_t)b * HDIM;
    for (int i = tid; i < HDIM; i += 256) row[i] = 0ULL;
  } else {
    for (int i = tid; i < HDIM; i += 256) rhpack[i] = 0ULL;
  }
}

// ---------------- batched e-projections: Bz/Br/A for all t ----------------
__global__ __launch_bounds__(256) void k_xproj(
    const int* __restrict__ tokens, const float* __restrict__ emb,
    const float* __restrict__ wzx, const float* __restrict__ wrx, const float* __restrict__ whx,
    const float* __restrict__ bzx, const float* __restrict__ bzh,
    const float* __restrict__ brx, const float* __restrict__ brh,
    const float* __restrict__ bhx, const float* __restrict__ bhh,
    float* __restrict__ ws) {
  __shared__ __align__(16) float es[16][EDIM];   // 32 KiB
  const int b   = blockIdx.x;
  const int t0  = (b & 15) * 16;
  const int c   = b >> 4;                 // 0..11
  const int tid = threadIdx.x;

  {
    int row = tid >> 4;
    int kc  = (tid & 15) * 32;
    int tok = tokens[t0 + row];
    const float4* ep = (const float4*)(emb + (size_t)tok * EDIM + kc);
    float4* dst = (float4*)&es[row][kc];
    #pragma unroll
    for (int q = 0; q < 8; q++) dst[q] = ep[q];
  }
  __syncthreads();

  const int mat = c >> 2;
  const int j   = (c & 3) * 256 + tid;
  const float* W; const float* b1; const float* b2; float* Xout;
  if (mat == 0)      { W = wzx; b1 = bzx; b2 = bzh; Xout = ws + WS_BZ; }
  else if (mat == 1) { W = wrx; b1 = brx; b2 = brh; Xout = ws + WS_BR; }
  else               { W = whx; b1 = bhx; b2 = bhh; Xout = ws + WS_A;  }

  const float4* wp = (const float4*)(W + (size_t)j * EDIM);
  const float bias = b1[j] + b2[j];
  float acc[16];
  #pragma unroll
  for (int tt = 0; tt < 16; tt++) acc[tt] = 0.0f;

  for (int k4 = 0; k4 < EDIM / 4; k4++) {
    float4 w = wp[k4];
    #pragma unroll
    for (int tt = 0; tt < 16; tt++) {
      float4 e4 = *(const float4*)&es[tt][k4 * 4];
      acc[tt] += w.x * e4.x + w.y * e4.y + w.z * e4.z + w.w * e4.w;
    }
  }
  #pragma unroll
  for (int tt = 0; tt < 16; tt++)
    Xout[(size_t)(t0 + tt) * HDIM + j] = acc[tt] + bias;
}

// ---------------- persistent GRU recurrence, fence-free sync, sentinel polls ----------------
__global__ __launch_bounds__(256) void k_recur(
    const float* __restrict__ wzh, const float* __restrict__ wrh, const float* __restrict__ whh,
    float* __restrict__ ws) {
  const int g    = blockIdx.x;
  const int tid  = threadIdx.x;
  const int lane = tid & 63;
  const int wv   = tid >> 6;
  const float* Bz = ws + WS_BZ;
  const float* Br = ws + WS_BR;
  const float* Aa = ws + WS_A;
  float* hseq = ws + WS_HSEQ;
  unsigned short* hseqb = (unsigned short*)(ws + WS_HSEQB);
  unsigned long long* hpack  = (unsigned long long*)(ws + WS_HPACK);
  unsigned long long* rhpack = (unsigned long long*)(ws + WS_RHPACK);

  const int j0 = 4 * tid;          // this thread's h-slice [j0, j0+4) — single producer WG
  const int r0 = g * RROWS;        // this WG's row base

  // register-resident weights: 3 x 8 rows x 4 cols = 96 floats
  float4 wz[RROWS], wr[RROWS], wh[RROWS];
  #pragma unroll
  for (int k = 0; k < RROWS; k++) {
    wz[k] = *(const float4*)(wzh + (size_t)(r0 + k) * HDIM + j0);
    wr[k] = *(const float4*)(wrh + (size_t)(r0 + k) * HDIM + j0);
    wh[k] = *(const float4*)(whh + (size_t)(r0 + k) * HDIM + j0);
  }

  __shared__ float redA[4][2 * RROWS];   // round A (z | r) — separate from round B (race fix)
  __shared__ float redB[4][RROWS];
  __shared__ float zs[RROWS];
  __shared__ float hloc[RROWS];
  if (tid < RROWS)
    hloc[tid] = __uint_as_float((unsigned)hpack[r0 + tid]);  // h0, written by k_init
  __syncthreads();

  for (int t = 0; t < T_STEPS; t++) {
    float bz_pre = 0.0f, br_pre = 0.0f, a_pre = 0.0f;
    if (tid < RROWS) {
      bz_pre = Bz[(size_t)t * HDIM + r0 + tid];
      a_pre  = Aa[(size_t)t * HDIM + r0 + tid];
    } else if (tid < 2 * RROWS) {
      br_pre = Br[(size_t)t * HDIM + r0 + (tid - RROWS)];
    }
    const unsigned long long ex = (unsigned long long)(unsigned)(t + 1);

    // ================= round A: z, r, publish r*h =================
    float hv0, hv1, hv2, hv3;
    {
      const unsigned long long* hp = hpack + (size_t)t * HDIM + j0;
      unsigned long long w0, w1, w2, w3;
      int it = 0;
      for (;;) {   // sentinel poll: word 0 only (8 B/iter instead of 32 B)
        w0 = __hip_atomic_load(hp + 0, __ATOMIC_RELAXED, __HIP_MEMORY_SCOPE_AGENT);
        if ((w0 >> 32) == ex) break;
        if (++it > (1 << 20)) break;
        __builtin_amdgcn_s_sleep(2);
      }
      for (;;) {   // remaining 3 words: same producer wave-store, nearly always ready
        w1 = __hip_atomic_load(hp + 1, __ATOMIC_RELAXED, __HIP_MEMORY_SCOPE_AGENT);
        w2 = __hip_atomic_load(hp + 2, __ATOMIC_RELAXED, __HIP_MEMORY_SCOPE_AGENT);
        w3 = __hip_atomic_load(hp + 3, __ATOMIC_RELAXED, __HIP_MEMORY_SCOPE_AGENT);
        if (((w1 >> 32) == ex) & ((w2 >> 32) == ex) & ((w3 >> 32) == ex)) break;
        if (++it > (1 << 20)) break;
        __builtin_amdgcn_s_sleep(1);
      }
      hv0 = __uint_as_float((unsigned)w0);
      hv1 = __uint_as_float((unsigned)w1);
      hv2 = __uint_as_float((unsigned)w2);
      hv3 = __uint_as_float((unsigned)w3);
    }

    float pz[RROWS], pr[RROWS];
    #pragma unroll
    for (int k = 0; k < RROWS; k++) {
      pz[k] = wz[k].x * hv0 + wz[k].y * hv1 + wz[k].z * hv2 + wz[k].w * hv3;
      pr[k] = wr[k].x * hv0 + wr[k].y * hv1 + wr[k].z * hv2 + wr[k].w * hv3;
    }
    #pragma unroll
    for (int m = 32; m >= 1; m >>= 1) {
      #pragma unroll
      for (int k = 0; k < RROWS; k++) {
        pz[k] += __shfl_xor(pz[k], m);
        pr[k] += __shfl_xor(pr[k], m);
      }
    }
    if (lane == 0) {
      #pragma unroll
      for (int k = 0; k < RROWS; k++) { redA[wv][k] = pz[k]; redA[wv][RROWS + k] = pr[k]; }
    }
    __syncthreads();
    if (tid < RROWS) {
      float u = redA[0][tid] + redA[1][tid] + redA[2][tid] + redA[3][tid];
      zs[tid] = sigmoidf_(bz_pre + u);
    } else if (tid < 2 * RROWS) {
      int k = tid - RROWS;
      float u = redA[0][tid] + redA[1][tid] + redA[2][tid] + redA[3][tid];
      float r = sigmoidf_(br_pre + u);
      float rh = r * hloc[k];
      __hip_atomic_store(&rhpack[r0 + k], pack_tv(t + 1, rh),
                         __ATOMIC_RELAXED, __HIP_MEMORY_SCOPE_AGENT);
    }

    // ================= round B: v = whh@(r*h), h_new =================
    float rv0, rv1, rv2, rv3;
    {
      const unsigned long long* rp = rhpack + j0;
      unsigned long long w0, w1, w2, w3;
      int it = 0;
      for (;;) {
        w0 = __hip_atomic_load(rp + 0, __ATOMIC_RELAXED, __HIP_MEMORY_SCOPE_AGENT);
        if ((w0 >> 32) == ex) break;
        if (++it > (1 << 20)) break;
        __builtin_amdgcn_s_sleep(2);
      }
      for (;;) {
        w1 = __hip_atomic_load(rp + 1, __ATOMIC_RELAXED, __HIP_MEMORY_SCOPE_AGENT);
        w2 = __hip_atomic_load(rp + 2, __ATOMIC_RELAXED, __HIP_MEMORY_SCOPE_AGENT);
        w3 = __hip_atomic_load(rp + 3, __ATOMIC_RELAXED, __HIP_MEMORY_SCOPE_AGENT);
        if (((w1 >> 32) == ex) & ((w2 >> 32) == ex) & ((w3 >> 32) == ex)) break;
        if (++it > (1 << 20)) break;
        __builtin_amdgcn_s_sleep(1);
      }
      rv0 = __uint_as_float((unsigned)w0);
      rv1 = __uint_as_float((unsigned)w1);
      rv2 = __uint_as_float((unsigned)w2);
      rv3 = __uint_as_float((unsigned)w3);
    }

    float ph[RROWS];
    #pragma unroll
    for (int k = 0; k < RROWS; k++)
      ph[k] = wh[k].x * rv0 + wh[k].y * rv1 + wh[k].z * rv2 + wh[k].w * rv3;
    #pragma unroll
    for (int m = 32; m >= 1; m >>= 1) {
      #pragma unroll
      for (int k = 0; k < RROWS; k++) ph[k] += __shfl_xor(ph[k], m);
    }
    if (lane == 0) {
      #pragma unroll
      for (int k = 0; k < RROWS; k++) redB[wv][k] = ph[k];
    }
    __syncthreads();
    if (tid < RROWS) {
      float v  = redB[0][tid] + redB[1][tid] + redB[2][tid] + redB[3][tid];
      float z  = zs[tid];
      float hk = hloc[tid];
      float hp_ = tanhf(a_pre + v);
      float hn = (1.0f - z) * hk + z * hp_;
      hloc[tid] = hn;
      __hip_atomic_store(&hpack[(size_t)(t + 1) * HDIM + r0 + tid], pack_tv(t + 2, hn),
                         __ATOMIC_RELAXED, __HIP_MEMORY_SCOPE_AGENT);
      hseq[(size_t)t * HDIM + r0 + tid] = hn;               // fp32 copy (refine + ref-exact dot)
      hseqb[(size_t)t * HDIM + r0 + tid] = f2bf(hn);        // bf16 copy (GEMM A)
    }
  }
}

// ---------------- logits GEMM (bf16 MFMA): [256,1024] @ out_w[32000,1024]^T + out_b ----------------
// Block: 256m x 128n, 4 waves each 64m x 128n. mfma_f32_16x16x32_bf16, fp32 accum.
// No LDS: fragments loaded per-lane from global (fully line-coalesced), out_w cvt'd in-reg.
__global__ __launch_bounds__(256) void k_gemm(
    const unsigned short* __restrict__ Abf, const float* __restrict__ outw,
    const float* __restrict__ outb, float* __restrict__ out) {
  const int tid  = threadIdx.x;
  const int lane = tid & 63;
  const int wv   = tid >> 6;
  const int n0   = blockIdx.x * 128;
  const int rA   = lane & 15;         // row-within-fragment (A:m, B:n, C:col)
  const int kg   = lane >> 4;         // k-group 0..3, 8 elems each

  f32x4 acc[4][8];
  #pragma unroll
  for (int i = 0; i < 4; i++)
    #pragma unroll
    for (int j = 0; j < 8; j++) acc[i][j] = (f32x4){0.f, 0.f, 0.f, 0.f};

  const int mbase = wv * 64 + rA;

  for (int k0 = 0; k0 < HDIM; k0 += 32) {
    const int ks = k0 + kg * 8;
    short8 afr[4];
    #pragma unroll
    for (int i = 0; i < 4; i++)
      afr[i] = *(const short8*)(Abf + (size_t)(mbase + i * 16) * HDIM + ks);

    short8 bfr[8];
    #pragma unroll
    for (int j = 0; j < 8; j++) {
      const float* bp = outw + (size_t)(n0 + j * 16 + rA) * HDIM + ks;
      float4 b0 = *(const float4*)(bp);
      float4 b1 = *(const float4*)(bp + 4);
      short8 s;
      s[0] = (short)f2bf(b0.x); s[1] = (short)f2bf(b0.y);
      s[2] = (short)f2bf(b0.z); s[3] = (short)f2bf(b0.w);
      s[4] = (short)f2bf(b1.x); s[5] = (short)f2bf(b1.y);
      s[6] = (short)f2bf(b1.z); s[7] = (short)f2bf(b1.w);
      bfr[j] = s;
    }

    #pragma unroll
    for (int i = 0; i < 4; i++)
      #pragma unroll
      for (int j = 0; j < 8; j++)
        acc[i][j] = __builtin_amdgcn_mfma_f32_16x16x32_bf16(afr[i], bfr[j], acc[i][j], 0, 0, 0);
  }

  // epilogue: C[m, n] : m = wv*64 + i*16 + (lane>>4)*4 + r, n = n0 + j*16 + (lane&15)
  float bias[8];
  #pragma unroll
  for (int j = 0; j < 8; j++) bias[j] = outb[n0 + j * 16 + rA];
  #pragma unroll
  for (int i = 0; i < 4; i++) {
    #pragma unroll
    for (int j = 0; j < 8; j++) {
      #pragma unroll
      for (int r = 0; r < 4; r++) {
        int m = wv * 64 + i * 16 + kg * 4 + r;
        out[(size_t)m * VDIM + n0 + j * 16 + rA] = acc[i][j][r] + bias[j];
      }
    }
  }
}

// ---------------- argmax with fp32 refinement ----------------
// bf16-GEMM logits can flip argmax; ids threshold punishes flips. Collect candidates within
// 0.25 of the row max (covers 2x worst bf16 error), recompute exactly in fp32, first-index tie.
__global__ __launch_bounds__(256) void k_argmax(const float* __restrict__ logits,
                                                const float* __restrict__ hseqf,
                                                const float* __restrict__ outw,
                                                const float* __restrict__ outb,
                                                float* __restrict__ outids) {
  const int t = blockIdx.x;
  const int tid = threadIdx.x;
  const float* row = logits + (size_t)t * VDIM;

  // pass 1: row max (value only)
  float mx = -3.4e38f;
  for (int v = tid; v < VDIM; v += 256) mx = fmaxf(mx, row[v]);
  __shared__ float sm[256];
  sm[tid] = mx;
  __syncthreads();
  for (int s = 128; s > 0; s >>= 1) {
    if (tid < s) sm[tid] = fmaxf(sm[tid], sm[tid + s]);
    __syncthreads();
  }
  const float bmax = sm[0];
  __syncthreads();

  // pass 2: collect candidate indices
  __shared__ int cand[64];
  __shared__ int cnt;
  if (tid == 0) cnt = 0;
  __syncthreads();
  const float cut = bmax - 0.25f;
  for (int v = tid; v < VDIM; v += 256) {
    if (row[v] >= cut) {
      int p = atomicAdd(&cnt, 1);
      if (p < 64) cand[p] = v;
    }
  }
  __syncthreads();
  int n = cnt < 64 ? cnt : 64;

  // pass 3: exact fp32 recompute of candidates
  __shared__ float cval[64];
  if (tid < n) {
    int v = cand[tid];
    const float* w = outw + (size_t)v * HDIM;
    const float* h = hseqf + (size_t)t * HDIM;
    float s0 = 0.f, s1 = 0.f, s2 = 0.f, s3 = 0.f;
    for (int k = 0; k < HDIM; k += 4) {
      float4 wf = *(const float4*)(w + k);
      float4 hf = *(const float4*)(h + k);
      s0 += wf.x * hf.x; s1 += wf.y * hf.y; s2 += wf.z * hf.z; s3 += wf.w * hf.w;
    }
    cval[tid] = (s0 + s1) + (s2 + s3) + outb[v];
  }
  __syncthreads();
  if (tid == 0) {
    float best = -3.4e38f; int bi = 0x7FFFFFFF;
    for (int i = 0; i < n; i++) {
      float v = cval[i]; int id = cand[i];
      if (v > best || (v == best && id < bi)) { best = v; bi = id; }
    }
    outids[t] = (float)bi;
  }
}

// ---------------- launch ----------------
extern "C" void kernel_launch(void* const* d_in, const int* in_sizes, int n_in,
                              void* d_out, int out_size, void* d_ws, size_t ws_size,
                              hipStream_t stream) {
  (void)in_sizes; (void)n_in; (void)out_size; (void)ws_size;
  const float* enc    = (const float*)d_in[0];
  const int*   tokens = (const int*)d_in[1];
  const float* emb    = (const float*)d_in[2];
  const float* wzx_w  = (const float*)d_in[3];
  const float* wzx_b  = (const float*)d_in[4];
  const float* wrx_w  = (const float*)d_in[5];
  const float* wrx_b  = (const float*)d_in[6];
  const float* whx_w  = (const float*)d_in[7];
  const float* whx_b  = (const float*)d_in[8];
  const float* wzh_w  = (const float*)d_in[9];
  const float* wzh_b  = (const float*)d_in[10];
  const float* wrh_w  = (const float*)d_in[11];
  const float* wrh_b  = (const float*)d_in[12];
  const float* whh_w  = (const float*)d_in[13];
  const float* whh_b  = (const float*)d_in[14];
  const float* out_w  = (const float*)d_in[15];
  const float* out_b  = (const float*)d_in[16];
  float* ws  = (float*)d_ws;
  float* out = (float*)d_out;

  k_init<<<dim3(T_STEPS + 2), dim3(256), 0, stream>>>(enc, ws);
  k_xproj<<<dim3(192), dim3(256), 0, stream>>>(tokens, emb, wzx_w, wrx_w, whx_w,
                                               wzx_b, wzh_b, wrx_b, wrh_b, whx_b, whh_b, ws);
  k_recur<<<dim3(RG), dim3(256), 0, stream>>>(wzh_w, wrh_w, whh_w, ws);
  k_gemm<<<dim3(VDIM / 128), dim3(256), 0, stream>>>((const unsigned short*)(ws + WS_HSEQB),
                                                     out_w, out_b, out);
  k_argmax<<<dim3(T_STEPS), dim3(256), 0, stream>>>(out, ws + WS_HSEQ, out_w, out_b,
                                                    out + (size_t)T_STEPS * VDIM);
}